// Round 6
// baseline (92.554 us; speedup 1.0000x reference)
//
#include <hip/hip_runtime.h>
#include <math.h>

#define BB 2
#define CCH 128
#define LL 4096
#define HEADS 4
#define DH 32
#define EPSV 1e-5f
#define NSP 4

typedef float f32x4 __attribute__((ext_vector_type(4)));
typedef short bf16x8 __attribute__((ext_vector_type(8)));

__device__ inline unsigned short f2bf(float x) {
    union { float f; unsigned u; } v; v.f = x;
    unsigned r = v.u + 0x7fffu + ((v.u >> 16) & 1u);
    return (unsigned short)(r >> 16);
}
__device__ inline float bfbits2f(unsigned bits_hi16) {
    union { unsigned u; float f; } v; v.u = bits_hi16; return v.f;
}
__device__ inline float bfu(unsigned short s) {
    union { unsigned u; float f; } v; v.u = (unsigned)s << 16; return v.f;
}
__device__ inline unsigned cvtpk(float lo, float hi) {
    unsigned r;
    asm("v_cvt_pk_bf16_f32 %0, %1, %2" : "=v"(r) : "v"(lo), "v"(hi));
    return r;
}

// ---------------- GN pass 1: partial sums (one block per channel) ----------------
__global__ __launch_bounds__(256) void gn_part(const float* __restrict__ x,
                                               float* __restrict__ ps, float* __restrict__ ps2) {
    const float* xp = x + (size_t)blockIdx.x * 4096;
    float s = 0.f, s2 = 0.f;
#pragma unroll
    for (int it = 0; it < 4; ++it) {
        float4 v = *(const float4*)(xp + it * 1024 + threadIdx.x * 4);
        s += v.x + v.y + v.z + v.w;
        s2 += v.x * v.x + v.y * v.y + v.z * v.z + v.w * v.w;
    }
    for (int off = 32; off; off >>= 1) {
        s += __shfl_down(s, off);
        s2 += __shfl_down(s2, off);
    }
    __shared__ float rs[4], rs2[4];
    int wave = threadIdx.x >> 6, lane = threadIdx.x & 63;
    if (lane == 0) { rs[wave] = s; rs2[wave] = s2; }
    __syncthreads();
    if (threadIdx.x == 0) {
        ps[blockIdx.x] = rs[0] + rs[1] + rs[2] + rs[3];
        ps2[blockIdx.x] = rs2[0] + rs2[1] + rs2[2] + rs2[3];
    }
}

// ---------------- GN pass 2: finalize stats ----------------
__global__ void gn_final(const float* __restrict__ ps, const float* __restrict__ ps2,
                         float* __restrict__ sm, float* __restrict__ sr) {
    int t = threadIdx.x;
    if (t >= 32) return;
    float s = 0.f, s2 = 0.f;
#pragma unroll
    for (int i = 0; i < 8; ++i) { s += ps[t * 8 + i]; s2 += ps2[t * 8 + i]; }
    float mean = s / 32768.f;
    float var = s2 / 32768.f - mean * mean;
    sm[t] = mean;
    sr[t] = rsqrtf(var + EPSV);
}

// ---------------- W prep: hi/lo bf16 split; Q rows pre-scaled by log2e/sqrt(dh) ----------------
__global__ __launch_bounds__(256) void prep_w(const float* __restrict__ w_qkv,
                                              const float* __restrict__ w_out,
                                              unsigned short* __restrict__ Wqh, unsigned short* __restrict__ Wql,
                                              unsigned short* __restrict__ Woh, unsigned short* __restrict__ Wol) {
    int i = blockIdx.x * 256 + threadIdx.x;
    const float qscale = 0.2550350f;  // log2(e)/sqrt(32)
    if (i < 49152) {
        float v = w_qkv[i];
        if (i < 16384) v *= qscale;  // Q rows (o<128)
        unsigned short h = f2bf(v);
        Wqh[i] = h;
        Wql[i] = f2bf(v - bfbits2f((unsigned)h << 16));
    } else {
        int j = i - 49152;
        float v = w_out[j];
        unsigned short h = f2bf(v);
        Woh[j] = h;
        Wol[j] = f2bf(v - bfbits2f((unsigned)h << 16));
    }
}

// ---------------- GN apply + transpose: x[b][c][l] -> xth/xtl[b][l][c] bf16 ----------------
__global__ __launch_bounds__(256) void gn_apply_t(const float* __restrict__ x,
                                                  const float* __restrict__ gw, const float* __restrict__ gb,
                                                  const float* __restrict__ sm, const float* __restrict__ sr,
                                                  unsigned short* __restrict__ xth, unsigned short* __restrict__ xtl) {
    int lt = blockIdx.x, ct = blockIdx.y, b = blockIdx.z;
    int c0 = ct * 32, l0 = lt * 64;
    __shared__ float wsh[32], bsh[32], msh[4], rsh[4];
    __shared__ unsigned short sh[32][72], sl[32][72];
    if (threadIdx.x < 32) { wsh[threadIdx.x] = gw[c0 + threadIdx.x]; bsh[threadIdx.x] = gb[c0 + threadIdx.x]; }
    if (threadIdx.x < 4) {
        int g = (c0 >> 3) + threadIdx.x;
        msh[threadIdx.x] = sm[b * 16 + g];
        rsh[threadIdx.x] = sr[b * 16 + g];
    }
    __syncthreads();
#pragma unroll
    for (int it = 0; it < 2; ++it) {
        int idx = it * 256 + threadIdx.x;  // over 512 float4 (32c x 16 f4)
        int cc = idx >> 4, l4 = idx & 15;
        float4 v = *(const float4*)(x + ((size_t)(b * CCH + c0 + cc)) * LL + l0 + l4 * 4);
        float mn = msh[cc >> 3], rstd = rsh[cc >> 3], w = wsh[cc], bv = bsh[cc];
        float a0 = (v.x - mn) * rstd * w + bv;
        float a1 = (v.y - mn) * rstd * w + bv;
        float a2 = (v.z - mn) * rstd * w + bv;
        float a3 = (v.w - mn) * rstd * w + bv;
        unsigned uh01 = cvtpk(a0, a1), uh23 = cvtpk(a2, a3);
        float r0 = a0 - bfbits2f(uh01 << 16), r1 = a1 - bfbits2f(uh01 & 0xffff0000u);
        float r2 = a2 - bfbits2f(uh23 << 16), r3 = a3 - bfbits2f(uh23 & 0xffff0000u);
        unsigned ul01 = cvtpk(r0, r1), ul23 = cvtpk(r2, r3);
        *(uint2*)&sh[cc][l4 * 4] = make_uint2(uh01, uh23);
        *(uint2*)&sl[cc][l4 * 4] = make_uint2(ul01, ul23);
    }
    __syncthreads();
    int l = threadIdx.x >> 2, c8 = threadIdx.x & 3;  // l in [0,64), 8 channels per thread
    unsigned hw[4], lw[4];
#pragma unroll
    for (int j = 0; j < 4; ++j) {
        int c = c8 * 8 + 2 * j;
        hw[j] = (unsigned)sh[c][l] | ((unsigned)sh[c + 1][l] << 16);
        lw[j] = (unsigned)sl[c][l] | ((unsigned)sl[c + 1][l] << 16);
    }
    *(uint4*)(xth + ((size_t)b * LL + l0 + l) * CCH + c0 + c8 * 8) = make_uint4(hw[0], hw[1], hw[2], hw[3]);
    *(uint4*)(xtl + ((size_t)b * LL + l0 + l) * CCH + c0 + c8 * 8) = make_uint4(lw[0], lw[1], lw[2], lw[3]);
}

// ---------------- QKV GEMM: D[l][o] = xt[l][c] * W[o][c], hi/lo split; 1-wave blocks ----------------
__global__ __launch_bounds__(64) void qkv_gemm(const unsigned short* __restrict__ xth,
                                               const unsigned short* __restrict__ xtl,
                                               const unsigned short* __restrict__ Wqh,
                                               const unsigned short* __restrict__ Wql,
                                               unsigned short* __restrict__ Qd,
                                               unsigned short* __restrict__ Kd,
                                               unsigned short* __restrict__ Vb) {
    int lt = blockIdx.x, og = blockIdx.y, b = blockIdx.z;
    int lane = threadIdx.x & 63, lm = lane & 15, lg = lane >> 4;
    int l0 = lt * 16;
    bf16x8 ah[4], al[4];
#pragma unroll
    for (int ks = 0; ks < 4; ++ks) {
        size_t off = ((size_t)b * LL + l0 + lm) * CCH + ks * 32 + 8 * lg;
        ah[ks] = *(const bf16x8*)(xth + off);
        al[ks] = *(const bf16x8*)(xtl + off);
    }
    f32x4 acc[8];
#pragma unroll
    for (int ot = 0; ot < 8; ++ot) acc[ot] = (f32x4){0.f, 0.f, 0.f, 0.f};
#pragma unroll
    for (int ot = 0; ot < 8; ++ot) {
#pragma unroll
        for (int ks = 0; ks < 4; ++ks) {
            size_t woff = (size_t)((og * 8 + ot) * 16 + lm) * CCH + ks * 32 + 8 * lg;
            bf16x8 wh = *(const bf16x8*)(Wqh + woff);
            bf16x8 wl = *(const bf16x8*)(Wql + woff);
            acc[ot] = __builtin_amdgcn_mfma_f32_16x16x32_bf16(ah[ks], wh, acc[ot], 0, 0, 0);
            acc[ot] = __builtin_amdgcn_mfma_f32_16x16x32_bf16(ah[ks], wl, acc[ot], 0, 0, 0);
            acc[ot] = __builtin_amdgcn_mfma_f32_16x16x32_bf16(al[ks], wh, acc[ot], 0, 0, 0);
        }
    }
    unsigned short* base = (og == 0) ? Qd : (og == 1) ? Kd : Vb;
#pragma unroll
    for (int ot = 0; ot < 8; ++ot) {
        int h = ot >> 1, d = (ot & 1) * 16 + lm;
        uint2 u;
        u.x = cvtpk(acc[ot][0], acc[ot][1]);
        u.y = cvtpk(acc[ot][2], acc[ot][3]);
        *(uint2*)(base + ((size_t)(b * HEADS + h) * DH + d) * LL + l0 + 4 * lg) = u;
    }
}

// ---------------- transpose Qd/Kd[bh][d][l] -> Qb/Kb[bh][l][d] ----------------
__global__ __launch_bounds__(256) void trQK(const unsigned short* __restrict__ Qd,
                                            const unsigned short* __restrict__ Kd,
                                            unsigned short* __restrict__ Qb,
                                            unsigned short* __restrict__ Kb) {
    int lt = blockIdx.x, bh = blockIdx.y, sel = blockIdx.z;
    const unsigned short* src = sel ? Kd : Qd;
    unsigned short* dst = sel ? Kb : Qb;
    int l0 = lt * 256;
    __shared__ unsigned short st[32][264];
#pragma unroll
    for (int it = 0; it < 4; ++it) {
        int idx = it * 256 + threadIdx.x;  // over 1024 uint4 (8 bf16 each)
        int d = idx >> 5, l8 = idx & 31;
        uint4 v = *(const uint4*)(src + ((size_t)bh * DH + d) * LL + l0 + l8 * 8);
        *(uint4*)&st[d][l8 * 8] = v;
    }
    __syncthreads();
    int t = threadIdx.x;  // l = l0 + t
    unsigned w[16];
#pragma unroll
    for (int dp = 0; dp < 16; ++dp)
        w[dp] = (unsigned)st[2 * dp][t] | ((unsigned)st[2 * dp + 1][t] << 16);
    uint4* dp4 = (uint4*)(dst + ((size_t)bh * LL + l0 + t) * DH);
#pragma unroll
    for (int i = 0; i < 4; ++i)
        dp4[i] = make_uint4(w[4 * i], w[4 * i + 1], w[4 * i + 2], w[4 * i + 3]);
}

// ---------------- MFMA flash attention: LDS-shared K/V, split-KV x4 ----------------
// grid.x = 1024 linear: id = qb*32 + (bh*4+sp)
__global__ __launch_bounds__(256) void attn_kernel(const unsigned short* __restrict__ Qp,
                                                   const unsigned short* __restrict__ Kp,
                                                   const unsigned short* __restrict__ Vp,
                                                   unsigned short* __restrict__ AccB, float* __restrict__ Ls) {
    __shared__ __align__(16) unsigned short Ksh[64][40];   // 80B rows
    __shared__ __align__(16) unsigned short Vsh[32][72];   // 144B rows
    __shared__ __align__(16) short Pl[4][2][16][72];
    int id = blockIdx.x;
    int combo = id & 31, qb = id >> 5;
    int bh = combo >> 2, sp = combo & 3;
    int wid = threadIdx.x >> 6, lane = threadIdx.x & 63, lm = lane & 15, lg = lane >> 4;
    int q0 = qb * 128 + wid * 32;
    int kv0 = sp * 1024;
    int t = threadIdx.x;

    const unsigned short* Kbh = Kp + (size_t)bh * LL * DH;
    const unsigned short* Vbh = Vp + (size_t)bh * DH * LL;

    bf16x8 qf[2];
    qf[0] = *(const bf16x8*)(Qp + ((size_t)bh * LL + q0 + lm) * DH + 8 * lg);
    qf[1] = *(const bf16x8*)(Qp + ((size_t)bh * LL + q0 + 16 + lm) * DH + 8 * lg);

    f32x4 accO[2][2];
#pragma unroll
    for (int qi = 0; qi < 2; ++qi)
#pragma unroll
        for (int dt = 0; dt < 2; ++dt) accO[qi][dt] = (f32x4){0.f, 0.f, 0.f, 0.f};
    float plsum[2] = {0.f, 0.f};
    const f32x4 cbias = {-24.f, -24.f, -24.f, -24.f};  // fixed softmax max, log2 domain

    int skv = t >> 2, ssl = (t & 3) * 8;   // K[64 kv][32 d]
    int svd = t >> 3, svs = (t & 7) * 8;   // V[32 d][64 kv]
    const uint4* gK = (const uint4*)(Kbh + (size_t)(kv0 + skv) * DH + ssl);
    const uint4* gV = (const uint4*)(Vbh + (size_t)svd * LL + kv0 + svs);
    uint4 kreg = *gK; gK += 256;
    uint4 vreg = *gV; gV += 8;

    for (int tt = 0; tt < 16; ++tt) {
        __syncthreads();
        *(uint4*)&Ksh[skv][ssl] = kreg;
        *(uint4*)&Vsh[svd][svs] = vreg;
        __syncthreads();
        if (tt < 15) { kreg = *gK; gK += 256; vreg = *gV; gV += 8; }

        bf16x8 kf[4];
#pragma unroll
        for (int kc = 0; kc < 4; ++kc)
            kf[kc] = *(const bf16x8*)&Ksh[kc * 16 + lm][lg * 8];
        f32x4 s[2][4];
#pragma unroll
        for (int qi = 0; qi < 2; ++qi)
#pragma unroll
            for (int kc = 0; kc < 4; ++kc)
                s[qi][kc] = __builtin_amdgcn_mfma_f32_16x16x32_bf16(kf[kc], qf[qi], cbias, 0, 0, 0);

        bf16x8 vf[2][2];
#pragma unroll
        for (int ch = 0; ch < 2; ++ch)
#pragma unroll
            for (int dt = 0; dt < 2; ++dt)
                vf[ch][dt] = *(const bf16x8*)&Vsh[dt * 16 + lm][ch * 32 + 8 * lg];

#pragma unroll
        for (int qi = 0; qi < 2; ++qi) {
#pragma unroll
            for (int kc = 0; kc < 4; ++kc) {
                float e0 = __builtin_amdgcn_exp2f(s[qi][kc][0]);
                float e1 = __builtin_amdgcn_exp2f(s[qi][kc][1]);
                float e2 = __builtin_amdgcn_exp2f(s[qi][kc][2]);
                float e3 = __builtin_amdgcn_exp2f(s[qi][kc][3]);
                plsum[qi] += (e0 + e1) + (e2 + e3);
                uint2 u;
                u.x = cvtpk(e0, e1);
                u.y = cvtpk(e2, e3);
                *(uint2*)&Pl[wid][qi][lm][kc * 16 + 4 * lg] = u;
            }
            bf16x8 pf[2];
#pragma unroll
            for (int ch = 0; ch < 2; ++ch)
                pf[ch] = *(const bf16x8*)&Pl[wid][qi][lm][ch * 32 + 8 * lg];
#pragma unroll
            for (int ch = 0; ch < 2; ++ch)
#pragma unroll
                for (int dt = 0; dt < 2; ++dt)
                    accO[qi][dt] = __builtin_amdgcn_mfma_f32_16x16x32_bf16(vf[ch][dt], pf[ch], accO[qi][dt], 0, 0, 0);
        }
    }

#pragma unroll
    for (int qi = 0; qi < 2; ++qi) {
        float pl = plsum[qi];
        pl += __shfl_xor(pl, 16);
        pl += __shfl_xor(pl, 32);
#pragma unroll
        for (int dt = 0; dt < 2; ++dt) {
            uint2 u;
            u.x = cvtpk(accO[qi][dt][0], accO[qi][dt][1]);
            u.y = cvtpk(accO[qi][dt][2], accO[qi][dt][3]);
            *(uint2*)(AccB + ((size_t)(sp * 8 + bh) * LL + q0 + qi * 16 + lm) * DH + dt * 16 + 4 * lg) = u;
        }
        if (lg == 0) Ls[(size_t)(sp * 8 + bh) * LL + q0 + qi * 16 + lm] = pl;
    }
}

// ---------------- out projection + 4-split combine + bias + residual ----------------
__global__ __launch_bounds__(256) void out_gemm(const unsigned short* __restrict__ AccB,
                                                const float* __restrict__ Ls,
                                                const unsigned short* __restrict__ Woh,
                                                const unsigned short* __restrict__ Wol,
                                                const float* __restrict__ bo,
                                                const float* __restrict__ x,
                                                float* __restrict__ out) {
    int lt = blockIdx.x, b = blockIdx.y;
    int wid = threadIdx.x >> 6, lane = threadIdx.x & 63, lm = lane & 15, lg = lane >> 4;
    int l0 = lt * 16;
    bf16x8 af[4];
#pragma unroll
    for (int ks = 0; ks < 4; ++ks) {
        int bh = b * HEADS + ks;
        float sum[8];
#pragma unroll
        for (int j = 0; j < 8; ++j) sum[j] = 0.f;
        float ls = 0.f;
#pragma unroll
        for (int sp = 0; sp < NSP; ++sp) {
            const unsigned short* ap = AccB + ((size_t)(sp * 8 + bh) * LL + l0 + lm) * DH + 8 * lg;
            uint4 v = *(const uint4*)ap;
            unsigned w0 = v.x, w1 = v.y, w2 = v.z, w3 = v.w;
            sum[0] += bfu((unsigned short)w0); sum[1] += bfu((unsigned short)(w0 >> 16));
            sum[2] += bfu((unsigned short)w1); sum[3] += bfu((unsigned short)(w1 >> 16));
            sum[4] += bfu((unsigned short)w2); sum[5] += bfu((unsigned short)(w2 >> 16));
            sum[6] += bfu((unsigned short)w3); sum[7] += bfu((unsigned short)(w3 >> 16));
            ls += Ls[(size_t)(sp * 8 + bh) * LL + l0 + lm];
        }
        float inv = 1.f / ls;
        union { unsigned u[4]; bf16x8 v; } cv;
        cv.u[0] = cvtpk(sum[0] * inv, sum[1] * inv);
        cv.u[1] = cvtpk(sum[2] * inv, sum[3] * inv);
        cv.u[2] = cvtpk(sum[4] * inv, sum[5] * inv);
        cv.u[3] = cvtpk(sum[6] * inv, sum[7] * inv);
        af[ks] = cv.v;
    }
    f32x4 acc[2];
    acc[0] = (f32x4){0.f, 0.f, 0.f, 0.f};
    acc[1] = (f32x4){0.f, 0.f, 0.f, 0.f};
#pragma unroll
    for (int oi = 0; oi < 2; ++oi) {
        int ot = wid * 2 + oi;
#pragma unroll
        for (int ks = 0; ks < 4; ++ks) {
            size_t woff = (size_t)(ot * 16 + lm) * CCH + ks * 32 + 8 * lg;
            bf16x8 wh = *(const bf16x8*)(Woh + woff);
            bf16x8 wl = *(const bf16x8*)(Wol + woff);
            acc[oi] = __builtin_amdgcn_mfma_f32_16x16x32_bf16(af[ks], wh, acc[oi], 0, 0, 0);
            acc[oi] = __builtin_amdgcn_mfma_f32_16x16x32_bf16(af[ks], wl, acc[oi], 0, 0, 0);
        }
    }
#pragma unroll
    for (int oi = 0; oi < 2; ++oi) {
        int oc = (wid * 2 + oi) * 16 + lm;
        float bias = bo[oc];
        size_t off = ((size_t)b * CCH + oc) * LL + l0 + 4 * lg;
        f32x4 xr = *(const f32x4*)(x + off);
        f32x4 r = acc[oi];
        r[0] += bias + xr[0];
        r[1] += bias + xr[1];
        r[2] += bias + xr[2];
        r[3] += bias + xr[3];
        *(f32x4*)(out + off) = r;
    }
}

extern "C" void kernel_launch(void* const* d_in, const int* in_sizes, int n_in,
                              void* d_out, int out_size, void* d_ws, size_t ws_size,
                              hipStream_t stream) {
    const float* x = (const float*)d_in[0];
    const float* gn_w = (const float*)d_in[1];
    const float* gn_b = (const float*)d_in[2];
    const float* w_qkv = (const float*)d_in[3];
    const float* w_out = (const float*)d_in[4];
    const float* b_out = (const float*)d_in[5];
    float* out = (float*)d_out;

    char* W = (char*)d_ws;
    unsigned short* xth = (unsigned short*)(W);              // [0,2M)
    unsigned short* xtl = (unsigned short*)(W + (2 << 20));  // [2,4M)
    unsigned short* Qd = (unsigned short*)(W + (4 << 20));   // [4,6M)
    unsigned short* Kd = (unsigned short*)(W + (6 << 20));   // [6,8M)
    unsigned short* Vb = (unsigned short*)(W + (8 << 20));   // [8,10M)
    unsigned short* Qb = (unsigned short*)(W + (10 << 20));  // [10,12M)
    unsigned short* Kb = (unsigned short*)(W + (12 << 20));  // [12,14M)
    unsigned short* AccB = (unsigned short*)(W);             // [0,8M): aliases xth/xtl/Qd/Kd, dead by attn
    float* Ls = (float*)(W + (14 << 20));                    // 512KB: 32 x 4096 f32
    float* ps = (float*)(W + (14 << 20) + (600 << 10));
    float* ps2 = ps + 256;
    float* sm = ps2 + 256;
    float* sr = sm + 32;
    unsigned short* Wqh = (unsigned short*)(sr + 32);
    unsigned short* Wql = Wqh + 49152;
    unsigned short* Woh = Wql + 49152;
    unsigned short* Wol = Woh + 16384;

    gn_part<<<dim3(256), dim3(256), 0, stream>>>(x, ps, ps2);
    gn_final<<<dim3(1), dim3(64), 0, stream>>>(ps, ps2, sm, sr);
    prep_w<<<dim3(256), dim3(256), 0, stream>>>(w_qkv, w_out, Wqh, Wql, Woh, Wol);
    gn_apply_t<<<dim3(64, 4, BB), dim3(256), 0, stream>>>(x, gn_w, gn_b, sm, sr, xth, xtl);
    qkv_gemm<<<dim3(256, 3, BB), dim3(64), 0, stream>>>(xth, xtl, Wqh, Wql, Qd, Kd, Vb);
    trQK<<<dim3(16, BB * HEADS, 2), dim3(256), 0, stream>>>(Qd, Kd, Qb, Kb);
    attn_kernel<<<dim3(1024), dim3(256), 0, stream>>>(Qb, Kb, Vb, AccB, Ls);
    out_gemm<<<dim3(256, BB), dim3(256), 0, stream>>>(AccB, Ls, Woh, Wol, b_out, x, out);
}

// Round 9
// 91.727 us; speedup vs baseline: 1.0090x; 1.0090x over previous
//
#include <hip/hip_runtime.h>
#include <math.h>

#define BB 2
#define CCH 128
#define LL 4096
#define HEADS 4
#define DH 32
#define EPSV 1e-5f
#define NSP 4

typedef float f32x4 __attribute__((ext_vector_type(4)));
typedef short bf16x8 __attribute__((ext_vector_type(8)));

__device__ inline unsigned short f2bf(float x) {
    union { float f; unsigned u; } v; v.f = x;
    unsigned r = v.u + 0x7fffu + ((v.u >> 16) & 1u);
    return (unsigned short)(r >> 16);
}
__device__ inline float bfbits2f(unsigned bits_hi16) {
    union { unsigned u; float f; } v; v.u = bits_hi16; return v.f;
}
__device__ inline float bfu(unsigned short s) {
    union { unsigned u; float f; } v; v.u = (unsigned)s << 16; return v.f;
}
__device__ inline unsigned cvtpk(float lo, float hi) {
    unsigned r;
    asm("v_cvt_pk_bf16_f32 %0, %1, %2" : "=v"(r) : "v"(lo), "v"(hi));
    return r;
}

// ---------------- GN pass 1: partial sums (one block per channel) ----------------
__global__ __launch_bounds__(256) void gn_part(const float* __restrict__ x,
                                               float* __restrict__ ps, float* __restrict__ ps2) {
    const float* xp = x + (size_t)blockIdx.x * 4096;
    float s = 0.f, s2 = 0.f;
#pragma unroll
    for (int it = 0; it < 4; ++it) {
        float4 v = *(const float4*)(xp + it * 1024 + threadIdx.x * 4);
        s += v.x + v.y + v.z + v.w;
        s2 += v.x * v.x + v.y * v.y + v.z * v.z + v.w * v.w;
    }
    for (int off = 32; off; off >>= 1) {
        s += __shfl_down(s, off);
        s2 += __shfl_down(s2, off);
    }
    __shared__ float rs[4], rs2[4];
    int wave = threadIdx.x >> 6, lane = threadIdx.x & 63;
    if (lane == 0) { rs[wave] = s; rs2[wave] = s2; }
    __syncthreads();
    if (threadIdx.x == 0) {
        ps[blockIdx.x] = rs[0] + rs[1] + rs[2] + rs[3];
        ps2[blockIdx.x] = rs2[0] + rs2[1] + rs2[2] + rs2[3];
    }
}

// ---------------- GN pass 2: finalize stats ----------------
__global__ void gn_final(const float* __restrict__ ps, const float* __restrict__ ps2,
                         float* __restrict__ sm, float* __restrict__ sr) {
    int t = threadIdx.x;
    if (t >= 32) return;
    float s = 0.f, s2 = 0.f;
#pragma unroll
    for (int i = 0; i < 8; ++i) { s += ps[t * 8 + i]; s2 += ps2[t * 8 + i]; }
    float mean = s / 32768.f;
    float var = s2 / 32768.f - mean * mean;
    sm[t] = mean;
    sr[t] = rsqrtf(var + EPSV);
}

// ---------------- W prep: hi/lo bf16 split; Q rows pre-scaled by log2e/sqrt(dh) ----------------
__global__ __launch_bounds__(256) void prep_w(const float* __restrict__ w_qkv,
                                              const float* __restrict__ w_out,
                                              unsigned short* __restrict__ Wqh, unsigned short* __restrict__ Wql,
                                              unsigned short* __restrict__ Woh, unsigned short* __restrict__ Wol) {
    int i = blockIdx.x * 256 + threadIdx.x;
    const float qscale = 0.2550350f;  // log2(e)/sqrt(32)
    if (i < 49152) {
        float v = w_qkv[i];
        if (i < 16384) v *= qscale;  // Q rows (o<128)
        unsigned short h = f2bf(v);
        Wqh[i] = h;
        Wql[i] = f2bf(v - bfbits2f((unsigned)h << 16));
    } else {
        int j = i - 49152;
        float v = w_out[j];
        unsigned short h = f2bf(v);
        Woh[j] = h;
        Wol[j] = f2bf(v - bfbits2f((unsigned)h << 16));
    }
}

// ---------------- GN apply + transpose: x[b][c][l] -> xth/xtl[b][l][c] bf16 ----------------
__global__ __launch_bounds__(256) void gn_apply_t(const float* __restrict__ x,
                                                  const float* __restrict__ gw, const float* __restrict__ gb,
                                                  const float* __restrict__ sm, const float* __restrict__ sr,
                                                  unsigned short* __restrict__ xth, unsigned short* __restrict__ xtl) {
    int lt = blockIdx.x, ct = blockIdx.y, b = blockIdx.z;
    int c0 = ct * 32, l0 = lt * 64;
    __shared__ float wsh[32], bsh[32], msh[4], rsh[4];
    __shared__ unsigned short sh[32][72], sl[32][72];
    if (threadIdx.x < 32) { wsh[threadIdx.x] = gw[c0 + threadIdx.x]; bsh[threadIdx.x] = gb[c0 + threadIdx.x]; }
    if (threadIdx.x < 4) {
        int g = (c0 >> 3) + threadIdx.x;
        msh[threadIdx.x] = sm[b * 16 + g];
        rsh[threadIdx.x] = sr[b * 16 + g];
    }
    __syncthreads();
#pragma unroll
    for (int it = 0; it < 2; ++it) {
        int idx = it * 256 + threadIdx.x;  // over 512 float4 (32c x 16 f4)
        int cc = idx >> 4, l4 = idx & 15;
        float4 v = *(const float4*)(x + ((size_t)(b * CCH + c0 + cc)) * LL + l0 + l4 * 4);
        float mn = msh[cc >> 3], rstd = rsh[cc >> 3], w = wsh[cc], bv = bsh[cc];
        float a0 = (v.x - mn) * rstd * w + bv;
        float a1 = (v.y - mn) * rstd * w + bv;
        float a2 = (v.z - mn) * rstd * w + bv;
        float a3 = (v.w - mn) * rstd * w + bv;
        unsigned uh01 = cvtpk(a0, a1), uh23 = cvtpk(a2, a3);
        float r0 = a0 - bfbits2f(uh01 << 16), r1 = a1 - bfbits2f(uh01 & 0xffff0000u);
        float r2 = a2 - bfbits2f(uh23 << 16), r3 = a3 - bfbits2f(uh23 & 0xffff0000u);
        unsigned ul01 = cvtpk(r0, r1), ul23 = cvtpk(r2, r3);
        *(uint2*)&sh[cc][l4 * 4] = make_uint2(uh01, uh23);
        *(uint2*)&sl[cc][l4 * 4] = make_uint2(ul01, ul23);
    }
    __syncthreads();
    int l = threadIdx.x >> 2, c8 = threadIdx.x & 3;  // l in [0,64), 8 channels per thread
    unsigned hw[4], lw[4];
#pragma unroll
    for (int j = 0; j < 4; ++j) {
        int c = c8 * 8 + 2 * j;
        hw[j] = (unsigned)sh[c][l] | ((unsigned)sh[c + 1][l] << 16);
        lw[j] = (unsigned)sl[c][l] | ((unsigned)sl[c + 1][l] << 16);
    }
    *(uint4*)(xth + ((size_t)b * LL + l0 + l) * CCH + c0 + c8 * 8) = make_uint4(hw[0], hw[1], hw[2], hw[3]);
    *(uint4*)(xtl + ((size_t)b * LL + l0 + l) * CCH + c0 + c8 * 8) = make_uint4(lw[0], lw[1], lw[2], lw[3]);
}

// ---------------- QKV GEMM: D[l][o] = xt[l][c] * W[o][c], hi/lo split; 1-wave blocks ----------------
__global__ __launch_bounds__(64) void qkv_gemm(const unsigned short* __restrict__ xth,
                                               const unsigned short* __restrict__ xtl,
                                               const unsigned short* __restrict__ Wqh,
                                               const unsigned short* __restrict__ Wql,
                                               unsigned short* __restrict__ Qd,
                                               unsigned short* __restrict__ Kd,
                                               unsigned short* __restrict__ Vb) {
    int lt = blockIdx.x, og = blockIdx.y, b = blockIdx.z;
    int lane = threadIdx.x & 63, lm = lane & 15, lg = lane >> 4;
    int l0 = lt * 16;
    bf16x8 ah[4], al[4];
#pragma unroll
    for (int ks = 0; ks < 4; ++ks) {
        size_t off = ((size_t)b * LL + l0 + lm) * CCH + ks * 32 + 8 * lg;
        ah[ks] = *(const bf16x8*)(xth + off);
        al[ks] = *(const bf16x8*)(xtl + off);
    }
    f32x4 acc[8];
#pragma unroll
    for (int ot = 0; ot < 8; ++ot) acc[ot] = (f32x4){0.f, 0.f, 0.f, 0.f};
#pragma unroll
    for (int ot = 0; ot < 8; ++ot) {
#pragma unroll
        for (int ks = 0; ks < 4; ++ks) {
            size_t woff = (size_t)((og * 8 + ot) * 16 + lm) * CCH + ks * 32 + 8 * lg;
            bf16x8 wh = *(const bf16x8*)(Wqh + woff);
            bf16x8 wl = *(const bf16x8*)(Wql + woff);
            acc[ot] = __builtin_amdgcn_mfma_f32_16x16x32_bf16(ah[ks], wh, acc[ot], 0, 0, 0);
            acc[ot] = __builtin_amdgcn_mfma_f32_16x16x32_bf16(ah[ks], wl, acc[ot], 0, 0, 0);
            acc[ot] = __builtin_amdgcn_mfma_f32_16x16x32_bf16(al[ks], wh, acc[ot], 0, 0, 0);
        }
    }
    unsigned short* base = (og == 0) ? Qd : (og == 1) ? Kd : Vb;
#pragma unroll
    for (int ot = 0; ot < 8; ++ot) {
        int h = ot >> 1, d = (ot & 1) * 16 + lm;
        uint2 u;
        u.x = cvtpk(acc[ot][0], acc[ot][1]);
        u.y = cvtpk(acc[ot][2], acc[ot][3]);
        *(uint2*)(base + ((size_t)(b * HEADS + h) * DH + d) * LL + l0 + 4 * lg) = u;
    }
}

// ---------------- transpose Qd/Kd[bh][d][l] -> Qb/Kb[bh][l][d] ----------------
__global__ __launch_bounds__(256) void trQK(const unsigned short* __restrict__ Qd,
                                            const unsigned short* __restrict__ Kd,
                                            unsigned short* __restrict__ Qb,
                                            unsigned short* __restrict__ Kb) {
    int lt = blockIdx.x, bh = blockIdx.y, sel = blockIdx.z;
    const unsigned short* src = sel ? Kd : Qd;
    unsigned short* dst = sel ? Kb : Qb;
    int l0 = lt * 256;
    __shared__ unsigned short st[32][264];
#pragma unroll
    for (int it = 0; it < 4; ++it) {
        int idx = it * 256 + threadIdx.x;  // over 1024 uint4 (8 bf16 each)
        int d = idx >> 5, l8 = idx & 31;
        uint4 v = *(const uint4*)(src + ((size_t)bh * DH + d) * LL + l0 + l8 * 8);
        *(uint4*)&st[d][l8 * 8] = v;
    }
    __syncthreads();
    int t = threadIdx.x;  // l = l0 + t
    unsigned w[16];
#pragma unroll
    for (int dp = 0; dp < 16; ++dp)
        w[dp] = (unsigned)st[2 * dp][t] | ((unsigned)st[2 * dp + 1][t] << 16);
    uint4* dp4 = (uint4*)(dst + ((size_t)bh * LL + l0 + t) * DH);
#pragma unroll
    for (int i = 0; i < 4; ++i)
        dp4[i] = make_uint4(w[4 * i], w[4 * i + 1], w[4 * i + 2], w[4 * i + 3]);
}

// ---------------- MFMA flash attention: single-barrier dbuf K/V, split-KV x4 ----------------
// ONLY change vs round 6: K/V staging double-buffered with one barrier per iter.
// Pl kept at round-6 layout [wid][qi] (separate slices -> no write/read aliasing across qi).
__global__ __launch_bounds__(256) void attn_kernel(const unsigned short* __restrict__ Qp,
                                                   const unsigned short* __restrict__ Kp,
                                                   const unsigned short* __restrict__ Vp,
                                                   unsigned short* __restrict__ AccB, float* __restrict__ Ls) {
    __shared__ __align__(16) unsigned short Ksh[2][64][40];   // 80B rows
    __shared__ __align__(16) unsigned short Vsh[2][32][72];   // 144B rows
    __shared__ __align__(16) short Pl[4][2][16][72];          // per-wave, per-qi (round-6 proven)
    int id = blockIdx.x;
    int combo = id & 31, qb = id >> 5;
    int bh = combo >> 2, sp = combo & 3;
    int wid = threadIdx.x >> 6, lane = threadIdx.x & 63, lm = lane & 15, lg = lane >> 4;
    int q0 = qb * 128 + wid * 32;
    int kv0 = sp * 1024;
    int t = threadIdx.x;

    const unsigned short* Kbh = Kp + (size_t)bh * LL * DH;
    const unsigned short* Vbh = Vp + (size_t)bh * DH * LL;

    bf16x8 qf[2];
    qf[0] = *(const bf16x8*)(Qp + ((size_t)bh * LL + q0 + lm) * DH + 8 * lg);
    qf[1] = *(const bf16x8*)(Qp + ((size_t)bh * LL + q0 + 16 + lm) * DH + 8 * lg);

    f32x4 accO[2][2];
#pragma unroll
    for (int qi = 0; qi < 2; ++qi)
#pragma unroll
        for (int dt = 0; dt < 2; ++dt) accO[qi][dt] = (f32x4){0.f, 0.f, 0.f, 0.f};
    float plsum[2] = {0.f, 0.f};
    const f32x4 cbias = {-24.f, -24.f, -24.f, -24.f};  // fixed softmax max, log2 domain

    int skv = t >> 2, ssl = (t & 3) * 8;   // K[64 kv][32 d]
    int svd = t >> 3, svs = (t & 7) * 8;   // V[32 d][64 kv]
    const uint4* gK = (const uint4*)(Kbh + (size_t)(kv0 + skv) * DH + ssl);
    const uint4* gV = (const uint4*)(Vbh + (size_t)svd * LL + kv0 + svs);
    uint4 kreg = *gK;
    uint4 vreg = *gV;

    for (int tt = 0; tt < 16; ++tt) {
        int cur = tt & 1;
        // write buf[cur]: readers of buf[cur] (iter tt-2) all passed barrier(tt-1) first
        *(uint4*)&Ksh[cur][skv][ssl] = kreg;
        *(uint4*)&Vsh[cur][svd][svs] = vreg;
        if (tt < 15) { gK += 256; gV += 8; kreg = *gK; vreg = *gV; }  // prefetch next tile
        __syncthreads();  // buf[cur] visible to all waves

        bf16x8 kf[4];
#pragma unroll
        for (int kc = 0; kc < 4; ++kc)
            kf[kc] = *(const bf16x8*)&Ksh[cur][kc * 16 + lm][lg * 8];
        f32x4 s[2][4];
#pragma unroll
        for (int qi = 0; qi < 2; ++qi)
#pragma unroll
            for (int kc = 0; kc < 4; ++kc)
                s[qi][kc] = __builtin_amdgcn_mfma_f32_16x16x32_bf16(kf[kc], qf[qi], cbias, 0, 0, 0);

        bf16x8 vf[2][2];
#pragma unroll
        for (int ch = 0; ch < 2; ++ch)
#pragma unroll
            for (int dt = 0; dt < 2; ++dt)
                vf[ch][dt] = *(const bf16x8*)&Vsh[cur][dt * 16 + lm][ch * 32 + 8 * lg];

#pragma unroll
        for (int qi = 0; qi < 2; ++qi) {
#pragma unroll
            for (int kc = 0; kc < 4; ++kc) {
                float e0 = __builtin_amdgcn_exp2f(s[qi][kc][0]);
                float e1 = __builtin_amdgcn_exp2f(s[qi][kc][1]);
                float e2 = __builtin_amdgcn_exp2f(s[qi][kc][2]);
                float e3 = __builtin_amdgcn_exp2f(s[qi][kc][3]);
                plsum[qi] += (e0 + e1) + (e2 + e3);
                uint2 u;
                u.x = cvtpk(e0, e1);
                u.y = cvtpk(e2, e3);
                *(uint2*)&Pl[wid][qi][lm][kc * 16 + 4 * lg] = u;
            }
            bf16x8 pf[2];
#pragma unroll
            for (int ch = 0; ch < 2; ++ch)
                pf[ch] = *(const bf16x8*)&Pl[wid][qi][lm][ch * 32 + 8 * lg];
#pragma unroll
            for (int ch = 0; ch < 2; ++ch)
#pragma unroll
                for (int dt = 0; dt < 2; ++dt)
                    accO[qi][dt] = __builtin_amdgcn_mfma_f32_16x16x32_bf16(vf[ch][dt], pf[ch], accO[qi][dt], 0, 0, 0);
        }
    }

#pragma unroll
    for (int qi = 0; qi < 2; ++qi) {
        float pl = plsum[qi];
        pl += __shfl_xor(pl, 16);
        pl += __shfl_xor(pl, 32);
#pragma unroll
        for (int dt = 0; dt < 2; ++dt) {
            uint2 u;
            u.x = cvtpk(accO[qi][dt][0], accO[qi][dt][1]);
            u.y = cvtpk(accO[qi][dt][2], accO[qi][dt][3]);
            *(uint2*)(AccB + ((size_t)(sp * 8 + bh) * LL + q0 + qi * 16 + lm) * DH + dt * 16 + 4 * lg) = u;
        }
        if (lg == 0) Ls[(size_t)(sp * 8 + bh) * LL + q0 + qi * 16 + lm] = pl;
    }
}

// ---------------- out projection + 4-split combine + bias + residual ----------------
__global__ __launch_bounds__(256) void out_gemm(const unsigned short* __restrict__ AccB,
                                                const float* __restrict__ Ls,
                                                const unsigned short* __restrict__ Woh,
                                                const unsigned short* __restrict__ Wol,
                                                const float* __restrict__ bo,
                                                const float* __restrict__ x,
                                                float* __restrict__ out) {
    int lt = blockIdx.x, b = blockIdx.y;
    int wid = threadIdx.x >> 6, lane = threadIdx.x & 63, lm = lane & 15, lg = lane >> 4;
    int l0 = lt * 16;
    bf16x8 af[4];
#pragma unroll
    for (int ks = 0; ks < 4; ++ks) {
        int bh = b * HEADS + ks;
        float sum[8];
#pragma unroll
        for (int j = 0; j < 8; ++j) sum[j] = 0.f;
        float ls = 0.f;
#pragma unroll
        for (int sp = 0; sp < NSP; ++sp) {
            const unsigned short* ap = AccB + ((size_t)(sp * 8 + bh) * LL + l0 + lm) * DH + 8 * lg;
            uint4 v = *(const uint4*)ap;
            unsigned w0 = v.x, w1 = v.y, w2 = v.z, w3 = v.w;
            sum[0] += bfu((unsigned short)w0); sum[1] += bfu((unsigned short)(w0 >> 16));
            sum[2] += bfu((unsigned short)w1); sum[3] += bfu((unsigned short)(w1 >> 16));
            sum[4] += bfu((unsigned short)w2); sum[5] += bfu((unsigned short)(w2 >> 16));
            sum[6] += bfu((unsigned short)w3); sum[7] += bfu((unsigned short)(w3 >> 16));
            ls += Ls[(size_t)(sp * 8 + bh) * LL + l0 + lm];
        }
        float inv = 1.f / ls;
        union { unsigned u[4]; bf16x8 v; } cv;
        cv.u[0] = cvtpk(sum[0] * inv, sum[1] * inv);
        cv.u[1] = cvtpk(sum[2] * inv, sum[3] * inv);
        cv.u[2] = cvtpk(sum[4] * inv, sum[5] * inv);
        cv.u[3] = cvtpk(sum[6] * inv, sum[7] * inv);
        af[ks] = cv.v;
    }
    f32x4 acc[2];
    acc[0] = (f32x4){0.f, 0.f, 0.f, 0.f};
    acc[1] = (f32x4){0.f, 0.f, 0.f, 0.f};
#pragma unroll
    for (int oi = 0; oi < 2; ++oi) {
        int ot = wid * 2 + oi;
#pragma unroll
        for (int ks = 0; ks < 4; ++ks) {
            size_t woff = (size_t)(ot * 16 + lm) * CCH + ks * 32 + 8 * lg;
            bf16x8 wh = *(const bf16x8*)(Woh + woff);
            bf16x8 wl = *(const bf16x8*)(Wol + woff);
            acc[oi] = __builtin_amdgcn_mfma_f32_16x16x32_bf16(af[ks], wh, acc[oi], 0, 0, 0);
            acc[oi] = __builtin_amdgcn_mfma_f32_16x16x32_bf16(af[ks], wl, acc[oi], 0, 0, 0);
        }
    }
#pragma unroll
    for (int oi = 0; oi < 2; ++oi) {
        int oc = (wid * 2 + oi) * 16 + lm;
        float bias = bo[oc];
        size_t off = ((size_t)b * CCH + oc) * LL + l0 + 4 * lg;
        f32x4 xr = *(const f32x4*)(x + off);
        f32x4 r = acc[oi];
        r[0] += bias + xr[0];
        r[1] += bias + xr[1];
        r[2] += bias + xr[2];
        r[3] += bias + xr[3];
        *(f32x4*)(out + off) = r;
    }
}

extern "C" void kernel_launch(void* const* d_in, const int* in_sizes, int n_in,
                              void* d_out, int out_size, void* d_ws, size_t ws_size,
                              hipStream_t stream) {
    const float* x = (const float*)d_in[0];
    const float* gn_w = (const float*)d_in[1];
    const float* gn_b = (const float*)d_in[2];
    const float* w_qkv = (const float*)d_in[3];
    const float* w_out = (const float*)d_in[4];
    const float* b_out = (const float*)d_in[5];
    float* out = (float*)d_out;

    char* W = (char*)d_ws;
    unsigned short* xth = (unsigned short*)(W);              // [0,2M)
    unsigned short* xtl = (unsigned short*)(W + (2 << 20));  // [2,4M)
    unsigned short* Qd = (unsigned short*)(W + (4 << 20));   // [4,6M)
    unsigned short* Kd = (unsigned short*)(W + (6 << 20));   // [6,8M)
    unsigned short* Vb = (unsigned short*)(W + (8 << 20));   // [8,10M)
    unsigned short* Qb = (unsigned short*)(W + (10 << 20));  // [10,12M)
    unsigned short* Kb = (unsigned short*)(W + (12 << 20));  // [12,14M)
    unsigned short* AccB = (unsigned short*)(W);             // [0,8M): aliases xth/xtl/Qd/Kd, dead by attn
    float* Ls = (float*)(W + (14 << 20));                    // 512KB: 32 x 4096 f32
    float* ps = (float*)(W + (14 << 20) + (600 << 10));
    float* ps2 = ps + 256;
    float* sm = ps2 + 256;
    float* sr = sm + 32;
    unsigned short* Wqh = (unsigned short*)(sr + 32);
    unsigned short* Wql = Wqh + 49152;
    unsigned short* Woh = Wql + 49152;
    unsigned short* Wol = Woh + 16384;

    gn_part<<<dim3(256), dim3(256), 0, stream>>>(x, ps, ps2);
    gn_final<<<dim3(1), dim3(64), 0, stream>>>(ps, ps2, sm, sr);
    prep_w<<<dim3(256), dim3(256), 0, stream>>>(w_qkv, w_out, Wqh, Wql, Woh, Wol);
    gn_apply_t<<<dim3(64, 4, BB), dim3(256), 0, stream>>>(x, gn_w, gn_b, sm, sr, xth, xtl);
    qkv_gemm<<<dim3(256, 3, BB), dim3(64), 0, stream>>>(xth, xtl, Wqh, Wql, Qd, Kd, Vb);
    trQK<<<dim3(16, BB * HEADS, 2), dim3(256), 0, stream>>>(Qd, Kd, Qb, Kb);
    attn_kernel<<<dim3(1024), dim3(256), 0, stream>>>(Qb, Kb, Vb, AccB, Ls);
    out_gemm<<<dim3(256, BB), dim3(256), 0, stream>>>(AccB, Ls, Woh, Wol, b_out, x, out);
}